// Round 1
// baseline (4049.773 us; speedup 1.0000x reference)
//
#include <hip/hip_runtime.h>

#define BB   16
#define CIN  256
#define COUT 256
#define WD   256
#define HH   64
#define WW   64
#define KW   9          // 3x3 taps per ci

// ---------------------------------------------------------------------------
// Kernel 1: style modulation  s[b][ci] = dot(w[b,:], style_w[ci,:]) + style_b[ci]
// ---------------------------------------------------------------------------
__global__ __launch_bounds__(256)
void style_kernel(const float* __restrict__ w,
                  const float* __restrict__ style_w,
                  const float* __restrict__ style_b,
                  float* __restrict__ s) {
    const int b  = blockIdx.x;
    const int ci = threadIdx.x;
    __shared__ float wsh[WD];
    wsh[ci] = w[b * WD + ci];
    __syncthreads();
    const float* row = style_w + ci * WD;
    float acc = style_b[ci];
    #pragma unroll 4
    for (int k = 0; k < WD; ++k) acc += wsh[k] * row[k];
    s[b * CIN + ci] = acc;
}

// ---------------------------------------------------------------------------
// Kernel 2: per-(b,co,16-row-tile) block.
//   Phase A: build demodulated weights wt[ci][3][3] in LDS (recomputed per
//            block -- 2304 mults, negligible vs conv work; avoids 38MB buffer).
//   Phase B: loop ci: stage x halo tile (18 rows x 66 cols) in LDS, each
//            thread owns 4 output rows at one column (register-blocked).
// ---------------------------------------------------------------------------
__global__ __launch_bounds__(256)
void modconv_kernel(const float* __restrict__ x,
                    const float* __restrict__ cw,
                    const float* __restrict__ s,
                    const float* __restrict__ scale_p,
                    float* __restrict__ out) {
    const int tile = blockIdx.x;   // 0..3 (16 output rows each)
    const int co   = blockIdx.y;
    const int b    = blockIdx.z;
    const int tid  = threadIdx.x;
    const float scale = scale_p[0];

    __shared__ float s_wt[CIN * KW];       // 9216 B
    __shared__ float s_x[18 * 66];         // 4752 B
    __shared__ float red[4];

    // ---- Phase A: modulate + demodulate weights ----
    const float* cwb = cw + (size_t)co * CIN * KW;
    const float* sb  = s + b * CIN;
    float sumsq = 0.f;
    for (int i = tid; i < CIN * KW; i += 256) {
        float v = cwb[i] * scale * sb[i / KW];
        s_wt[i] = v;
        sumsq += v * v;
    }
    // wave64 reduce then cross-wave via LDS
    #pragma unroll
    for (int off = 32; off > 0; off >>= 1)
        sumsq += __shfl_down(sumsq, off);
    if ((tid & 63) == 0) red[tid >> 6] = sumsq;
    __syncthreads();
    const float total = red[0] + red[1] + red[2] + red[3];
    const float demod = rsqrtf(total + 1e-8f);
    for (int i = tid; i < CIN * KW; i += 256) s_wt[i] *= demod;
    // barrier folded into first iteration's top barrier below

    // ---- Phase B: convolution ----
    const int tx = tid & 63;       // output column
    const int tr = tid >> 6;       // 0..3: owns rows y0 + tr*4 + {0..3}
    const int y0 = tile * 16;
    float acc[4] = {0.f, 0.f, 0.f, 0.f};

    for (int ci = 0; ci < CIN; ++ci) {
        __syncthreads();           // protect s_x (and, at ci==0, s_wt scaling)
        const float* xb = x + ((size_t)(b * CIN + ci)) * (HH * WW);
        // stage 18x66 halo tile (rows y0-1 .. y0+16, cols -1 .. 64)
        for (int idx = tid; idx < 18 * 66; idx += 256) {
            const int r  = idx / 66;
            const int c  = idx % 66;
            const int yg = y0 - 1 + r;
            const int xg = c - 1;
            float v = 0.f;
            if (yg >= 0 && yg < HH && xg >= 0 && xg < WW)
                v = xb[yg * WW + xg];
            s_x[idx] = v;
        }
        __syncthreads();

        const float* wr = s_wt + ci * KW;
        const float w0 = wr[0], w1 = wr[1], w2 = wr[2];
        const float w3 = wr[3], w4 = wr[4], w5 = wr[5];
        const float w6 = wr[6], w7 = wr[7], w8 = wr[8];

        const int rbase = tr * 4;
        float xv[6][3];
        #pragma unroll
        for (int j = 0; j < 6; ++j)
            #pragma unroll
            for (int k = 0; k < 3; ++k)
                xv[j][k] = s_x[(rbase + j) * 66 + tx + k];

        #pragma unroll
        for (int i = 0; i < 4; ++i) {
            acc[i] += w0 * xv[i    ][0] + w1 * xv[i    ][1] + w2 * xv[i    ][2]
                    + w3 * xv[i + 1][0] + w4 * xv[i + 1][1] + w5 * xv[i + 1][2]
                    + w6 * xv[i + 2][0] + w7 * xv[i + 2][1] + w8 * xv[i + 2][2];
        }
    }

    float* ob = out + (((size_t)(b * COUT + co)) * HH + y0) * WW + tx;
    #pragma unroll
    for (int i = 0; i < 4; ++i) ob[(tr * 4 + i) * WW] = acc[i];
}

// ---------------------------------------------------------------------------
extern "C" void kernel_launch(void* const* d_in, const int* in_sizes, int n_in,
                              void* d_out, int out_size, void* d_ws, size_t ws_size,
                              hipStream_t stream) {
    const float* x       = (const float*)d_in[0];
    const float* w       = (const float*)d_in[1];
    const float* cw      = (const float*)d_in[2];
    const float* style_w = (const float*)d_in[3];
    const float* style_b = (const float*)d_in[4];
    const float* scale_p = (const float*)d_in[5];
    float*       out     = (float*)d_out;
    float*       s       = (float*)d_ws;   // [B, CIN] styles, 16 KB

    style_kernel<<<dim3(BB), 256, 0, stream>>>(w, style_w, style_b, s);
    modconv_kernel<<<dim3(4, COUT, BB), 256, 0, stream>>>(x, cw, s, scale_p, out);
}

// Round 2
// 146.295 us; speedup vs baseline: 27.6823x; 27.6823x over previous
//
#include <hip/hip_runtime.h>
#include <hip/hip_bf16.h>

#define BB   16
#define CIN  256
#define COUT 256
#define WD   256
#define HH   64
#define WWS  64
#define NSP  4096      // HH*WWS
#define KW   9

typedef __attribute__((ext_vector_type(8))) short short8;
typedef __attribute__((ext_vector_type(4))) float f32x4;
typedef unsigned short ushort_t;

// workspace layout
#define S_OFF 0
#define S_BYTES (BB*CIN*4)                       // 16 KB
#define WT_OFF (S_BYTES)
#define WT_BYTES (BB*9*COUT*CIN*2)               // 18.87 MB
#define X_OFF (WT_OFF + WT_BYTES)
#define X_BYTES (BB*NSP*CIN*2)                   // 33.55 MB
#define WS_NEEDED ((size_t)(X_OFF + X_BYTES))

__device__ inline ushort_t f2bf(float f) {
    __hip_bfloat16 h = __float2bfloat16(f);
    return __builtin_bit_cast(ushort_t, h);
}

// ---------------------------------------------------------------------------
// Kernel 1: style modulation  s[b][ci] = dot(w[b,:], style_w[ci,:]) + style_b
// ---------------------------------------------------------------------------
__global__ __launch_bounds__(256)
void style_kernel(const float* __restrict__ w,
                  const float* __restrict__ style_w,
                  const float* __restrict__ style_b,
                  float* __restrict__ s) {
    const int b  = blockIdx.x;
    const int ci = threadIdx.x;
    __shared__ float wsh[WD];
    wsh[ci] = w[b * WD + ci];
    __syncthreads();
    const float* row = style_w + ci * WD;
    float acc = style_b[ci];
    #pragma unroll 4
    for (int k = 0; k < WD; ++k) acc += wsh[k] * row[k];
    s[b * CIN + ci] = acc;
}

// ---------------------------------------------------------------------------
// Kernel 2: demodulated weights -> bf16, layout [b][tap][co][ci]
// ---------------------------------------------------------------------------
__global__ __launch_bounds__(256)
void wt_kernel(const float* __restrict__ cw, const float* __restrict__ s,
               const float* __restrict__ scale_p, ushort_t* __restrict__ wt) {
    const int co = blockIdx.x, b = blockIdx.y, ci = threadIdx.x;
    const float sv = s[b * CIN + ci] * scale_p[0];
    const float* cp = cw + ((size_t)co * CIN + ci) * KW;
    float v[9];
    float ss = 0.f;
    #pragma unroll
    for (int t = 0; t < 9; ++t) { v[t] = cp[t] * sv; ss += v[t] * v[t]; }
    #pragma unroll
    for (int off = 32; off > 0; off >>= 1) ss += __shfl_down(ss, off);
    __shared__ float red[4];
    if ((ci & 63) == 0) red[ci >> 6] = ss;
    __syncthreads();
    const float dm = rsqrtf(red[0] + red[1] + red[2] + red[3] + 1e-8f);
    #pragma unroll
    for (int t = 0; t < 9; ++t)
        wt[((size_t)(b * 9 + t) * COUT + co) * CIN + ci] = f2bf(v[t] * dm);
}

// ---------------------------------------------------------------------------
// Kernel 3: x NCHW fp32 -> NHWC bf16  (xo[b][sp][ci])
// ---------------------------------------------------------------------------
__global__ __launch_bounds__(256)
void xpose_kernel(const float* __restrict__ x, ushort_t* __restrict__ xo) {
    const int spt = blockIdx.x;   // 64 spatial tiles of 64
    const int cit = blockIdx.y;   // 4 ci tiles of 64
    const int b   = blockIdx.z;
    const int t   = threadIdx.x;
    __shared__ ushort_t tile[64 * 68];   // [sp][ci], pad 68
    const int sp0 = spt * 64, ci0 = cit * 64;
    {
        const int spq = t & 15, cil = t >> 4;   // cil 0..15
        #pragma unroll
        for (int i = 0; i < 4; ++i) {
            const int ci = cil + i * 16;
            const float4 v = *(const float4*)(x + ((size_t)(b * CIN + ci0 + ci)) * NSP + sp0 + spq * 4);
            tile[(spq * 4 + 0) * 68 + ci] = f2bf(v.x);
            tile[(spq * 4 + 1) * 68 + ci] = f2bf(v.y);
            tile[(spq * 4 + 2) * 68 + ci] = f2bf(v.z);
            tile[(spq * 4 + 3) * 68 + ci] = f2bf(v.w);
        }
    }
    __syncthreads();
    {
        const int g4 = t & 15, sp = t >> 4;
        #pragma unroll
        for (int i = 0; i < 4; ++i) {
            const int spp = sp + i * 16;
            uint2 v = *(const uint2*)&tile[spp * 68 + g4 * 4];
            *(uint2*)(xo + ((size_t)(b * NSP + sp0 + spp)) * CIN + ci0 + g4 * 4) = v;
        }
    }
}

// ---------------------------------------------------------------------------
// Kernel 4: implicit-GEMM conv via MFMA.
//   256 blocks (16 b x 16 ntiles, XCD-swizzled), 512 threads (8 waves 2Mx4N).
//   BM=256 co, BN=256 spatial (4 rows), K = 8 ci-chunks x 9 taps.
// ---------------------------------------------------------------------------
__global__ __launch_bounds__(512, 2)
void conv_mfma_kernel(const ushort_t* __restrict__ wt,   // [b][9][256][256]
                      const ushort_t* __restrict__ xo,   // [b][4096][256]
                      float* __restrict__ out) {
    // XCD swizzle: all 16 ntiles of a batch land on one XCD (wgid%8 fixed)
    const int wg    = blockIdx.x + 16 * blockIdx.y;          // 0..255
    const int b     = (wg & 7) + 8 * ((wg >> 3) & 1);
    const int ntile = wg >> 4;
    const int y0    = ntile * 4;

    const int tid  = threadIdx.x;
    const int lane = tid & 63;
    const int wid  = tid >> 6;
    const int wm   = wid >> 2;     // 0..1  (co half)
    const int wn   = wid & 3;      // 0..3  (spatial row / 64-col group)
    const int l15  = lane & 15;
    const int lg   = lane >> 4;    // 0..3

    __shared__ __align__(16) ushort_t lds_x[6 * 66 * 40];     // 31680 B
    __shared__ __align__(16) ushort_t lds_a[2][256 * 40];     // 40960 B

    // ---- per-thread staging tasks ----
    int  x_lw[3]; long x_gb[3]; bool x_val[3];
    #pragma unroll
    for (int i = 0; i < 3; ++i) {
        const int idx = tid + 512 * i;          // 1536 tasks: [6 r][64 c][4 g]
        const int r = idx >> 8, rem = idx & 255;
        const int cm1 = rem >> 2, g = idx & 3;
        const int y = y0 - 1 + r;
        x_val[i] = (y >= 0 && y < HH);
        const int yc = y < 0 ? 0 : (y > HH - 1 ? HH - 1 : y);
        x_lw[i] = (r * 66 + cm1 + 1) * 40 + g * 8;
        x_gb[i] = ((long)(b * NSP + yc * WWS + cm1)) * CIN + g * 8;
    }
    int a_lw[2]; long a_gb[2];
    #pragma unroll
    for (int i = 0; i < 2; ++i) {
        const int idx = tid + 512 * i;          // 1024 tasks: [256 co][4 g]
        const int co = idx >> 2, g = idx & 3;
        a_lw[i] = co * 40 + g * 8;
        a_gb[i] = (long)co * CIN + g * 8;
    }
    const long wt_b = (long)b * 9 * COUT * CIN;

    const int a_base = (wm * 128 + l15) * 40 + lg * 8;
    const int b_base = (wn * 66 + l15) * 40 + lg * 8;

    f32x4 acc[8][4];
    #pragma unroll
    for (int mi = 0; mi < 8; ++mi)
        #pragma unroll
        for (int ni = 0; ni < 4; ++ni) acc[mi][ni] = (f32x4){0.f, 0.f, 0.f, 0.f};

    // zero halo columns (cols 0 and 65), stay zero forever
    if (tid < 60) {
        const int r = tid / 10, rem2 = tid % 10;
        const int c = (rem2 >= 5) ? 65 : 0, q = rem2 % 5;
        *(uint4*)&lds_x[(r * 66 + c) * 40 + q * 8] = make_uint4(0, 0, 0, 0);
    }

    // ---- prologue: x chunk 0 -> regs; A step0 -> LDS; A step1 -> regs ----
    uint4 rX[3], rA[2];
    #pragma unroll
    for (int i = 0; i < 3; ++i)
        rX[i] = x_val[i] ? *(const uint4*)(xo + x_gb[i]) : make_uint4(0, 0, 0, 0);
    #pragma unroll
    for (int i = 0; i < 2; ++i) {
        uint4 v = *(const uint4*)(wt + wt_b + a_gb[i]);            // tap0, chunk0
        *(uint4*)&lds_a[0][a_lw[i]] = v;
    }
    #pragma unroll
    for (int i = 0; i < 2; ++i)
        rA[i] = *(const uint4*)(wt + wt_b + (long)1 * COUT * CIN + a_gb[i]); // tap1

    for (int chunk = 0; chunk < 8; ++chunk) {
        const int cpar = chunk & 1;
        __syncthreads();                          // prev-chunk x readers done
        #pragma unroll
        for (int i = 0; i < 3; ++i) *(uint4*)&lds_x[x_lw[i]] = rX[i];
        __syncthreads();                          // x tile visible

        #pragma unroll
        for (int ky = 0; ky < 3; ++ky)
        #pragma unroll
        for (int kx = 0; kx < 3; ++kx) {
            const int tap = ky * 3 + kx;
            if (tap > 0) __syncthreads();         // step barrier

            // write A[step+1] into the buffer not being read this step
            {
                ushort_t* wb = lds_a[cpar ^ ((tap + 1) & 1)];
                #pragma unroll
                for (int i = 0; i < 2; ++i) *(uint4*)&wb[a_lw[i]] = rA[i];
            }
            // issue loads for A[step+2] (in flight across this step's MFMAs)
            {
                const int tap2   = (tap + 2) % 9;
                const int chunk2 = chunk + (tap + 2) / 9;
                if (chunk2 < 8) {
                    #pragma unroll
                    for (int i = 0; i < 2; ++i)
                        rA[i] = *(const uint4*)(wt + wt_b + (long)tap2 * COUT * CIN
                                                + chunk2 * 32 + a_gb[i]);
                }
            }
            // issue next chunk's x loads mid-chunk
            if (tap == 4 && chunk < 7) {
                #pragma unroll
                for (int i = 0; i < 3; ++i)
                    rX[i] = x_val[i] ? *(const uint4*)(xo + x_gb[i] + (chunk + 1) * 32)
                                     : make_uint4(0, 0, 0, 0);
            }

            // ---- MFMA: 32 per wave per step ----
            const ushort_t* ab = lds_a[cpar ^ (tap & 1)] + a_base;
            short8 af[8];
            #pragma unroll
            for (int mi = 0; mi < 8; ++mi) af[mi] = *(const short8*)(ab + mi * 640);
            short8 bf[4];
            #pragma unroll
            for (int ni = 0; ni < 4; ++ni)
                bf[ni] = *(const short8*)(lds_x + b_base + (ky * 66 + kx) * 40 + ni * 640);
            #pragma unroll
            for (int mi = 0; mi < 8; ++mi)
                #pragma unroll
                for (int ni = 0; ni < 4; ++ni)
                    acc[mi][ni] = __builtin_amdgcn_mfma_f32_16x16x32_bf16(
                        af[mi], bf[ni], acc[mi][ni], 0, 0, 0);
        }
    }

    // ---- epilogue: C frag row = co = (lane>>4)*4+reg, col = spatial ----
    const int co_b = wm * 128 + lg * 4;
    const int sp_b = ntile * 256 + wn * 64 + l15;
    #pragma unroll
    for (int mi = 0; mi < 8; ++mi)
        #pragma unroll
        for (int ni = 0; ni < 4; ++ni)
            #pragma unroll
            for (int rg = 0; rg < 4; ++rg) {
                const int co = co_b + mi * 16 + rg;
                const int sp = sp_b + ni * 16;
                out[((long)(b * COUT + co)) * NSP + sp] = acc[mi][ni][rg];
            }
}

// ---------------------------------------------------------------------------
// Fallback fp32 direct conv (round-1 baseline) if workspace is too small.
// ---------------------------------------------------------------------------
__global__ __launch_bounds__(256)
void modconv_kernel(const float* __restrict__ x,
                    const float* __restrict__ cw,
                    const float* __restrict__ s,
                    const float* __restrict__ scale_p,
                    float* __restrict__ out) {
    const int tile = blockIdx.x;
    const int co   = blockIdx.y;
    const int b    = blockIdx.z;
    const int tid  = threadIdx.x;
    const float scale = scale_p[0];

    __shared__ float s_wt[CIN * KW];
    __shared__ float s_x[18 * 66];
    __shared__ float red[4];

    const float* cwb = cw + (size_t)co * CIN * KW;
    const float* sb  = s + b * CIN;
    float sumsq = 0.f;
    for (int i = tid; i < CIN * KW; i += 256) {
        float v = cwb[i] * scale * sb[i / KW];
        s_wt[i] = v;
        sumsq += v * v;
    }
    #pragma unroll
    for (int off = 32; off > 0; off >>= 1) sumsq += __shfl_down(sumsq, off);
    if ((tid & 63) == 0) red[tid >> 6] = sumsq;
    __syncthreads();
    const float demod = rsqrtf(red[0] + red[1] + red[2] + red[3] + 1e-8f);
    for (int i = tid; i < CIN * KW; i += 256) s_wt[i] *= demod;

    const int tx = tid & 63;
    const int tr = tid >> 6;
    const int y0 = tile * 16;
    float acc[4] = {0.f, 0.f, 0.f, 0.f};

    for (int ci = 0; ci < CIN; ++ci) {
        __syncthreads();
        const float* xb = x + ((size_t)(b * CIN + ci)) * (HH * WWS);
        for (int idx = tid; idx < 18 * 66; idx += 256) {
            const int r = idx / 66, c = idx % 66;
            const int yg = y0 - 1 + r, xg = c - 1;
            float v = 0.f;
            if (yg >= 0 && yg < HH && xg >= 0 && xg < WWS) v = xb[yg * WWS + xg];
            s_x[idx] = v;
        }
        __syncthreads();
        const float* wr = s_wt + ci * KW;
        const float w0 = wr[0], w1 = wr[1], w2 = wr[2];
        const float w3 = wr[3], w4 = wr[4], w5 = wr[5];
        const float w6 = wr[6], w7 = wr[7], w8 = wr[8];
        const int rbase = tr * 4;
        float xv[6][3];
        #pragma unroll
        for (int j = 0; j < 6; ++j)
            #pragma unroll
            for (int k = 0; k < 3; ++k) xv[j][k] = s_x[(rbase + j) * 66 + tx + k];
        #pragma unroll
        for (int i = 0; i < 4; ++i)
            acc[i] += w0 * xv[i][0] + w1 * xv[i][1] + w2 * xv[i][2]
                    + w3 * xv[i+1][0] + w4 * xv[i+1][1] + w5 * xv[i+1][2]
                    + w6 * xv[i+2][0] + w7 * xv[i+2][1] + w8 * xv[i+2][2];
    }
    float* ob = out + (((size_t)(b * COUT + co)) * HH + y0) * WWS + tx;
    #pragma unroll
    for (int i = 0; i < 4; ++i) ob[(tr * 4 + i) * WWS] = acc[i];
}

// ---------------------------------------------------------------------------
extern "C" void kernel_launch(void* const* d_in, const int* in_sizes, int n_in,
                              void* d_out, int out_size, void* d_ws, size_t ws_size,
                              hipStream_t stream) {
    const float* x       = (const float*)d_in[0];
    const float* w       = (const float*)d_in[1];
    const float* cw      = (const float*)d_in[2];
    const float* style_w = (const float*)d_in[3];
    const float* style_b = (const float*)d_in[4];
    const float* scale_p = (const float*)d_in[5];
    float*       out     = (float*)d_out;

    float*    s    = (float*)d_ws;
    ushort_t* wswt = (ushort_t*)((char*)d_ws + WT_OFF);
    ushort_t* wsx  = (ushort_t*)((char*)d_ws + X_OFF);

    style_kernel<<<dim3(BB), 256, 0, stream>>>(w, style_w, style_b, s);

    if (ws_size >= WS_NEEDED) {
        wt_kernel<<<dim3(COUT, BB), 256, 0, stream>>>(cw, s, scale_p, wswt);
        xpose_kernel<<<dim3(64, 4, BB), 256, 0, stream>>>(x, wsx);
        conv_mfma_kernel<<<dim3(16, 16), 512, 0, stream>>>(wswt, wsx, out);
    } else {
        modconv_kernel<<<dim3(4, COUT, BB), 256, 0, stream>>>(x, cw, s, scale_p, out);
    }
}